// Round 1
// 1111.123 us; speedup vs baseline: 1.1698x; 1.1698x over previous
//
#include <hip/hip_runtime.h>
#include <hip/hip_bf16.h>

#define M_ROWS 100000
#define NFEAT 1024
#define NCOMP 512
#define NHID 256
#define NB 782            // ceil(100000/128)
#define NC (NB * 8)
#define LDA 72            // padded LDS row stride for legacy path

// workspace layout (bytes)
#define WS_WCT   0
#define WS_W1T   1048576
#define WS_W2T   1310720
#define WS_SAGG  1572864
#define WS_CVAL  1576960
#define WS_CIDX  1627008
#define WS_XBF   1677312ULL                       // 1024-aligned
#define WS_HBF   (WS_XBF + 204800000ULL)          // x_bf16: 100000*1024*2
#define WS_REQ   (WS_HBF + 102400000ULL + 262144ULL)  // h_bf16 + OOB slack

using bf16x8 = __attribute__((ext_vector_type(8))) __bf16;
using f32x4  = __attribute__((ext_vector_type(4))) float;

__device__ inline unsigned short f2bf(float f) {
  return __builtin_bit_cast(unsigned short, (__bf16)f);
}

// global -> LDS direct copy, 16 B per lane. LDS dest is wave-uniform base + lane*16.
__device__ __forceinline__ void g2l16(const void* g, void* l) {
  __builtin_amdgcn_global_load_lds(
      (const __attribute__((address_space(1))) unsigned int*)(unsigned long long)g,
      (__attribute__((address_space(3))) unsigned int*)(unsigned int)(unsigned long long)l,
      16, 0, 0);
}

// ---------------------------------------------------------------- prep (legacy)
__global__ void k_prep(const float* __restrict__ Wc, const float* __restrict__ W1,
                       const float* __restrict__ W2, const float* __restrict__ b3,
                       unsigned short* __restrict__ WcT, unsigned short* __restrict__ W1T,
                       unsigned short* __restrict__ W2T, float* __restrict__ slide_agg,
                       float* __restrict__ att) {
  int tid = blockIdx.x * blockDim.x + threadIdx.x;
  int stride = gridDim.x * blockDim.x;
  for (int i = tid; i < NCOMP * NFEAT; i += stride) {
    int n = i >> 10, k = i & (NFEAT - 1);
    WcT[i] = f2bf(Wc[k * NCOMP + n]);
  }
  for (int i = tid; i < NHID * NCOMP; i += stride) {
    int n = i >> 9, k = i & (NCOMP - 1);
    W1T[i] = f2bf(W1[k * NHID + n]);
    W2T[i] = f2bf(W2[k * NHID + n]);
  }
  for (int i = tid; i < 2 * NCOMP; i += stride) slide_agg[i] = 0.f;
  float b30 = b3[0], b31 = b3[1];
  for (int i = tid; i < M_ROWS; i += stride) {
    *(float2*)(att + 2 * i) = make_float2(b30, b31);
  }
}

// ---------------------------------------------------------------- prep2: legacy + x -> bf16
__global__ void k_prep2(const float* __restrict__ x, const float* __restrict__ Wc,
                        const float* __restrict__ W1, const float* __restrict__ W2,
                        const float* __restrict__ b3, unsigned short* __restrict__ xbf,
                        unsigned short* __restrict__ WcT, unsigned short* __restrict__ W1T,
                        unsigned short* __restrict__ W2T, float* __restrict__ slide_agg,
                        float* __restrict__ att) {
  int tid = blockIdx.x * blockDim.x + threadIdx.x;
  int stride = gridDim.x * blockDim.x;
  for (int i = tid; i < M_ROWS * NFEAT / 4; i += stride) {
    float4 v = ((const float4*)x)[i];
    ((ushort4*)xbf)[i] = make_ushort4(f2bf(v.x), f2bf(v.y), f2bf(v.z), f2bf(v.w));
  }
  for (int i = tid; i < NCOMP * NFEAT; i += stride) {
    int n = i >> 10, k = i & (NFEAT - 1);
    WcT[i] = f2bf(Wc[k * NCOMP + n]);
  }
  for (int i = tid; i < NHID * NCOMP; i += stride) {
    int n = i >> 9, k = i & (NCOMP - 1);
    W1T[i] = f2bf(W1[k * NHID + n]);
    W2T[i] = f2bf(W2[k * NHID + n]);
  }
  for (int i = tid; i < 2 * NCOMP; i += stride) slide_agg[i] = 0.f;
  float b30 = b3[0], b31 = b3[1];
  for (int i = tid; i < M_ROWS; i += stride) {
    *(float2*)(att + 2 * i) = make_float2(b30, b31);
  }
}

// ---------------------------------------------------------------- GEMM1 (m97 structure):
// h = relu(x@Wc+bc), A/B staged via global_load_lds, linear LDS, 2 barriers per K-step.
__global__ __launch_bounds__(256, 2)
void k_gemm1n(const unsigned short* __restrict__ xbf, const unsigned short* __restrict__ WcT,
              const float* __restrict__ bc, float* __restrict__ h,
              unsigned short* __restrict__ hbf) {
  __shared__ unsigned short Al[128 * 64];
  __shared__ unsigned short Bl[128 * 64];
  const int xcd = blockIdx.x & 7;
  const int local = blockIdx.x >> 3;
  const int nt = local & 3;
  const int mt = (local >> 2) * 8 + xcd;
  if (mt >= NB) return;
  const int m0 = mt * 128, n0 = nt * 128;
  const int t = threadIdx.x;
  const int wave = t >> 6, lane = t & 63;
  const int wm = wave & 1, wn = wave >> 1;
  const int lo = lane & 15, quad = lane >> 4;

  // staging: 16 chunks of 8 rows x 64 cols (1024 B); wave w stages chunks w*4..w*4+3
  const int srow = lane >> 3;          // row within chunk
  const int scol = (lane & 7) * 8;     // shorts within row
  const unsigned short* Ag = xbf + (size_t)(m0 + wave * 32 + srow) * NFEAT + scol;
  const unsigned short* Bg = WcT + (size_t)(n0 + wave * 32 + srow) * NFEAT + scol;
  unsigned short* Alw = &Al[wave * 4 * 512];
  unsigned short* Blw = &Bl[wave * 4 * 512];

  f32x4 acc[4][4] = {};

  for (int kk = 0; kk < NFEAT; kk += 64) {
    #pragma unroll
    for (int i = 0; i < 4; i++) {
      g2l16(Ag + (size_t)(i * 8) * NFEAT + kk, Alw + i * 512);
      g2l16(Bg + (size_t)(i * 8) * NFEAT + kk, Blw + i * 512);
    }
    asm volatile("s_waitcnt vmcnt(0)" ::: "memory");
    __syncthreads();
    #pragma unroll
    for (int ks = 0; ks < 2; ks++) {
      bf16x8 af[4], bfr[4];
      #pragma unroll
      for (int mf = 0; mf < 4; mf++)
        af[mf] = *(const bf16x8*)(&Al[(wm * 64 + mf * 16 + lo) * 64 + ks * 32 + quad * 8]);
      #pragma unroll
      for (int nf = 0; nf < 4; nf++)
        bfr[nf] = *(const bf16x8*)(&Bl[(wn * 64 + nf * 16 + lo) * 64 + ks * 32 + quad * 8]);
      #pragma unroll
      for (int mf = 0; mf < 4; mf++)
        #pragma unroll
        for (int nf = 0; nf < 4; nf++)
          acc[mf][nf] = __builtin_amdgcn_mfma_f32_16x16x32_bf16(af[mf], bfr[nf], acc[mf][nf], 0, 0, 0);
    }
    __syncthreads();
  }
  #pragma unroll
  for (int nf = 0; nf < 4; nf++) {
    int col = n0 + wn * 64 + nf * 16 + lo;
    float bias = bc[col];
    #pragma unroll
    for (int mf = 0; mf < 4; mf++) {
      int rb = m0 + wm * 64 + mf * 16 + quad * 4;
      #pragma unroll
      for (int r = 0; r < 4; r++) {
        int row = rb + r;
        if (row < M_ROWS) {
          float v = fmaxf(acc[mf][nf][r] + bias, 0.f);
          h[(size_t)row * NCOMP + col] = v;
          hbf[(size_t)row * NCOMP + col] = f2bf(v);
        }
      }
    }
  }
}

// ---------------------------------------------------------------- GEMM2 (m97 structure):
// gated attention partials; A = h_bf16, B1/B2 = W1T/W2T, all via global_load_lds.
__global__ __launch_bounds__(512, 2)
void k_gemm2n(const unsigned short* __restrict__ hbf, const unsigned short* __restrict__ W1T,
              const unsigned short* __restrict__ W2T, const float* __restrict__ b1,
              const float* __restrict__ b2, const float* __restrict__ W3,
              float* __restrict__ att) {
  __shared__ unsigned short Al[128 * 64];
  __shared__ unsigned short B1l[128 * 64];
  __shared__ unsigned short B2l[128 * 64];
  const int xcd = blockIdx.x & 7;
  const int local = blockIdx.x >> 3;
  const int nt = local & 1;
  const int mt = (local >> 1) * 8 + xcd;
  if (mt >= NB) return;
  const int m0 = mt * 128, n0 = nt * 128;
  const int t = threadIdx.x;
  const int wave = t >> 6, lane = t & 63;
  const int wm = wave & 3, wn = wave >> 2;   // 4 m-waves x 2 n-waves, 32x64 per wave
  const int lo = lane & 15, quad = lane >> 4;

  // staging: 16 chunks per tile, 8 waves -> 2 chunks each
  const int srow = lane >> 3;
  const int scol = (lane & 7) * 8;
  const unsigned short* Ag  = hbf + (size_t)(m0 + wave * 16 + srow) * NCOMP + scol;
  const unsigned short* B1g = W1T + (size_t)(n0 + wave * 16 + srow) * NCOMP + scol;
  const unsigned short* B2g = W2T + (size_t)(n0 + wave * 16 + srow) * NCOMP + scol;
  unsigned short* Alw = &Al[wave * 1024];
  unsigned short* B1w = &B1l[wave * 1024];
  unsigned short* B2w = &B2l[wave * 1024];

  f32x4 acc1[2][4] = {};
  f32x4 acc2[2][4] = {};

  for (int kk = 0; kk < NCOMP; kk += 64) {
    #pragma unroll
    for (int i = 0; i < 2; i++) {
      g2l16(Ag  + (size_t)(i * 8) * NCOMP + kk, Alw + i * 512);
      g2l16(B1g + (size_t)(i * 8) * NCOMP + kk, B1w + i * 512);
      g2l16(B2g + (size_t)(i * 8) * NCOMP + kk, B2w + i * 512);
    }
    asm volatile("s_waitcnt vmcnt(0)" ::: "memory");
    __syncthreads();
    #pragma unroll
    for (int ks = 0; ks < 2; ks++) {
      bf16x8 af[2];
      #pragma unroll
      for (int mf = 0; mf < 2; mf++)
        af[mf] = *(const bf16x8*)(&Al[(wm * 32 + mf * 16 + lo) * 64 + ks * 32 + quad * 8]);
      #pragma unroll
      for (int nf = 0; nf < 4; nf++) {
        bf16x8 b1f = *(const bf16x8*)(&B1l[(wn * 64 + nf * 16 + lo) * 64 + ks * 32 + quad * 8]);
        acc1[0][nf] = __builtin_amdgcn_mfma_f32_16x16x32_bf16(af[0], b1f, acc1[0][nf], 0, 0, 0);
        acc1[1][nf] = __builtin_amdgcn_mfma_f32_16x16x32_bf16(af[1], b1f, acc1[1][nf], 0, 0, 0);
        bf16x8 b2f = *(const bf16x8*)(&B2l[(wn * 64 + nf * 16 + lo) * 64 + ks * 32 + quad * 8]);
        acc2[0][nf] = __builtin_amdgcn_mfma_f32_16x16x32_bf16(af[0], b2f, acc2[0][nf], 0, 0, 0);
        acc2[1][nf] = __builtin_amdgcn_mfma_f32_16x16x32_bf16(af[1], b2f, acc2[1][nf], 0, 0, 0);
      }
    }
    __syncthreads();
  }
  // a = tanh(G1+b1)*sigmoid(G2+b2); partial att = a @ W3 (reduce over this block's 128 cols)
  float p[2][4][2] = {};
  #pragma unroll
  for (int nf = 0; nf < 4; nf++) {
    int col = n0 + wn * 64 + nf * 16 + lo;
    float bb1 = b1[col], bb2 = b2[col];
    float w30 = W3[col * 2], w31 = W3[col * 2 + 1];
    #pragma unroll
    for (int mf = 0; mf < 2; mf++)
      #pragma unroll
      for (int r = 0; r < 4; r++) {
        float g1 = acc1[mf][nf][r] + bb1;
        float g2 = acc2[mf][nf][r] + bb2;
        float e = __expf(-2.f * g1);
        float th = (1.f - e) / (1.f + e);
        float sg = 1.f / (1.f + __expf(-g2));
        float a = th * sg;
        p[mf][r][0] += a * w30;
        p[mf][r][1] += a * w31;
      }
  }
  #pragma unroll
  for (int mask = 1; mask < 16; mask <<= 1)
    #pragma unroll
    for (int mf = 0; mf < 2; mf++)
      #pragma unroll
      for (int r = 0; r < 4; r++) {
        p[mf][r][0] += __shfl_xor(p[mf][r][0], mask, 64);
        p[mf][r][1] += __shfl_xor(p[mf][r][1], mask, 64);
      }
  if (lo == 0) {
    #pragma unroll
    for (int mf = 0; mf < 2; mf++)
      #pragma unroll
      for (int r = 0; r < 4; r++) {
        int row = m0 + wm * 32 + mf * 16 + quad * 4 + r;
        if (row < M_ROWS) {
          atomicAdd(&att[row * 2],     p[mf][r][0]);
          atomicAdd(&att[row * 2 + 1], p[mf][r][1]);
        }
      }
  }
}

// ---------------------------------------------------------------- legacy GEMM1
__global__ __launch_bounds__(256, 2)
void k_gemm1(const float* __restrict__ x, const unsigned short* __restrict__ WcT,
             const float* __restrict__ bc, float* __restrict__ h) {
  __shared__ unsigned short Al[128 * LDA];
  __shared__ unsigned short Bl[128 * LDA];
  const int xcd = blockIdx.x & 7;
  const int local = blockIdx.x >> 3;
  const int nt = local & 3;
  const int mt = (local >> 2) * 8 + xcd;
  if (mt >= NB) return;
  const int m0 = mt * 128, n0 = nt * 128;
  const int t = threadIdx.x;
  const int wave = t >> 6, lane = t & 63;
  const int wm = wave & 1, wn = wave >> 1;
  const int lo = lane & 15, quad = lane >> 4;

  const int arow = t >> 4, ach = t & 15;
  const int brow = t >> 3, bch = t & 7;

  f32x4 acc[4][4] = {};
  float4 aPre[8];
  uint4  bPre[4];

  {
    #pragma unroll
    for (int i = 0; i < 8; i++) {
      int gr = m0 + arow + i * 16;
      aPre[i] = (gr < M_ROWS) ? *(const float4*)(x + (size_t)gr * NFEAT + ach * 4)
                              : make_float4(0.f, 0.f, 0.f, 0.f);
    }
    #pragma unroll
    for (int i = 0; i < 4; i++)
      bPre[i] = *(const uint4*)(WcT + (n0 + brow + i * 32) * NFEAT + bch * 8);
  }

  for (int kk = 0; kk < NFEAT; kk += 64) {
    #pragma unroll
    for (int i = 0; i < 8; i++) {
      float4 v = aPre[i];
      *(ushort4*)(&Al[(arow + i * 16) * LDA + ach * 4]) =
          make_ushort4(f2bf(v.x), f2bf(v.y), f2bf(v.z), f2bf(v.w));
    }
    #pragma unroll
    for (int i = 0; i < 4; i++)
      *(uint4*)(&Bl[(brow + i * 32) * LDA + bch * 8]) = bPre[i];
    __syncthreads();

    if (kk + 64 < NFEAT) {
      int kn = kk + 64;
      #pragma unroll
      for (int i = 0; i < 8; i++) {
        int gr = m0 + arow + i * 16;
        aPre[i] = (gr < M_ROWS) ? *(const float4*)(x + (size_t)gr * NFEAT + kn + ach * 4)
                                : make_float4(0.f, 0.f, 0.f, 0.f);
      }
      #pragma unroll
      for (int i = 0; i < 4; i++)
        bPre[i] = *(const uint4*)(WcT + (n0 + brow + i * 32) * NFEAT + kn + bch * 8);
    }

    #pragma unroll
    for (int ks = 0; ks < 2; ks++) {
      bf16x8 af[4], bfr[4];
      #pragma unroll
      for (int mf = 0; mf < 4; mf++)
        af[mf] = *(const bf16x8*)(&Al[(wm * 64 + mf * 16 + lo) * LDA + ks * 32 + quad * 8]);
      #pragma unroll
      for (int nf = 0; nf < 4; nf++)
        bfr[nf] = *(const bf16x8*)(&Bl[(wn * 64 + nf * 16 + lo) * LDA + ks * 32 + quad * 8]);
      #pragma unroll
      for (int mf = 0; mf < 4; mf++)
        #pragma unroll
        for (int nf = 0; nf < 4; nf++)
          acc[mf][nf] = __builtin_amdgcn_mfma_f32_16x16x32_bf16(af[mf], bfr[nf], acc[mf][nf], 0, 0, 0);
    }
    __syncthreads();
  }
  #pragma unroll
  for (int nf = 0; nf < 4; nf++) {
    int col = n0 + wn * 64 + nf * 16 + lo;
    float bias = bc[col];
    #pragma unroll
    for (int mf = 0; mf < 4; mf++) {
      int rb = m0 + wm * 64 + mf * 16 + quad * 4;
      #pragma unroll
      for (int r = 0; r < 4; r++) {
        int row = rb + r;
        if (row < M_ROWS) {
          float v = acc[mf][nf][r] + bias;
          h[(size_t)row * NCOMP + col] = fmaxf(v, 0.f);
        }
      }
    }
  }
}

// ---------------------------------------------------------------- legacy GEMM2
__global__ __launch_bounds__(512, 2)
void k_gemm2(const float* __restrict__ h, const unsigned short* __restrict__ W1T,
             const unsigned short* __restrict__ W2T, const float* __restrict__ b1,
             const float* __restrict__ b2, const float* __restrict__ W3,
             float* __restrict__ att) {
  __shared__ unsigned short Al[128 * LDA];
  __shared__ unsigned short B1l[128 * LDA];
  __shared__ unsigned short B2l[128 * LDA];
  const int xcd = blockIdx.x & 7;
  const int local = blockIdx.x >> 3;
  const int nt = local & 1;
  const int mt = (local >> 1) * 8 + xcd;
  if (mt >= NB) return;
  const int m0 = mt * 128, n0 = nt * 128;
  const int t = threadIdx.x;
  const int wave = t >> 6, lane = t & 63;
  const int wm = wave & 3, wn = wave >> 2;
  const int lo = lane & 15, quad = lane >> 4;

  const int arow = t >> 4, ach = t & 15;
  const int brow = t >> 3, bch = t & 7;

  f32x4 acc1[2][4] = {};
  f32x4 acc2[2][4] = {};
  float4 aPre[4];
  uint4  b1Pre[2], b2Pre[2];

  {
    #pragma unroll
    for (int i = 0; i < 4; i++) {
      int gr = m0 + arow + i * 32;
      aPre[i] = (gr < M_ROWS) ? *(const float4*)(h + (size_t)gr * NCOMP + ach * 4)
                              : make_float4(0.f, 0.f, 0.f, 0.f);
    }
    #pragma unroll
    for (int i = 0; i < 2; i++) {
      int src = (n0 + brow + i * 64) * NCOMP + bch * 8;
      b1Pre[i] = *(const uint4*)(W1T + src);
      b2Pre[i] = *(const uint4*)(W2T + src);
    }
  }

  for (int kk = 0; kk < NCOMP; kk += 64) {
    #pragma unroll
    for (int i = 0; i < 4; i++) {
      float4 v = aPre[i];
      *(ushort4*)(&Al[(arow + i * 32) * LDA + ach * 4]) =
          make_ushort4(f2bf(v.x), f2bf(v.y), f2bf(v.z), f2bf(v.w));
    }
    #pragma unroll
    for (int i = 0; i < 2; i++) {
      *(uint4*)(&B1l[(brow + i * 64) * LDA + bch * 8]) = b1Pre[i];
      *(uint4*)(&B2l[(brow + i * 64) * LDA + bch * 8]) = b2Pre[i];
    }
    __syncthreads();

    if (kk + 64 < NCOMP) {
      int kn = kk + 64;
      #pragma unroll
      for (int i = 0; i < 4; i++) {
        int gr = m0 + arow + i * 32;
        aPre[i] = (gr < M_ROWS) ? *(const float4*)(h + (size_t)gr * NCOMP + kn + ach * 4)
                                : make_float4(0.f, 0.f, 0.f, 0.f);
      }
      #pragma unroll
      for (int i = 0; i < 2; i++) {
        int src = (n0 + brow + i * 64) * NCOMP + kn + bch * 8;
        b1Pre[i] = *(const uint4*)(W1T + src);
        b2Pre[i] = *(const uint4*)(W2T + src);
      }
    }

    #pragma unroll
    for (int ks = 0; ks < 2; ks++) {
      bf16x8 af[2], b1f[4], b2f[4];
      #pragma unroll
      for (int mf = 0; mf < 2; mf++)
        af[mf] = *(const bf16x8*)(&Al[(wm * 32 + mf * 16 + lo) * LDA + ks * 32 + quad * 8]);
      #pragma unroll
      for (int nf = 0; nf < 4; nf++) {
        b1f[nf] = *(const bf16x8*)(&B1l[(wn * 64 + nf * 16 + lo) * LDA + ks * 32 + quad * 8]);
        b2f[nf] = *(const bf16x8*)(&B2l[(wn * 64 + nf * 16 + lo) * LDA + ks * 32 + quad * 8]);
      }
      #pragma unroll
      for (int mf = 0; mf < 2; mf++)
        #pragma unroll
        for (int nf = 0; nf < 4; nf++) {
          acc1[mf][nf] = __builtin_amdgcn_mfma_f32_16x16x32_bf16(af[mf], b1f[nf], acc1[mf][nf], 0, 0, 0);
          acc2[mf][nf] = __builtin_amdgcn_mfma_f32_16x16x32_bf16(af[mf], b2f[nf], acc2[mf][nf], 0, 0, 0);
        }
    }
    __syncthreads();
  }
  float p[2][4][2] = {};
  #pragma unroll
  for (int nf = 0; nf < 4; nf++) {
    int col = n0 + wn * 64 + nf * 16 + lo;
    float bb1 = b1[col], bb2 = b2[col];
    float w30 = W3[col * 2], w31 = W3[col * 2 + 1];
    #pragma unroll
    for (int mf = 0; mf < 2; mf++)
      #pragma unroll
      for (int r = 0; r < 4; r++) {
        float g1 = acc1[mf][nf][r] + bb1;
        float g2 = acc2[mf][nf][r] + bb2;
        float e = __expf(-2.f * g1);
        float th = (1.f - e) / (1.f + e);
        float sg = 1.f / (1.f + __expf(-g2));
        float a = th * sg;
        p[mf][r][0] += a * w30;
        p[mf][r][1] += a * w31;
      }
  }
  #pragma unroll
  for (int mask = 1; mask < 16; mask <<= 1)
    #pragma unroll
    for (int mf = 0; mf < 2; mf++)
      #pragma unroll
      for (int r = 0; r < 4; r++) {
        p[mf][r][0] += __shfl_xor(p[mf][r][0], mask, 64);
        p[mf][r][1] += __shfl_xor(p[mf][r][1], mask, 64);
      }
  if (lo == 0) {
    #pragma unroll
    for (int mf = 0; mf < 2; mf++)
      #pragma unroll
      for (int r = 0; r < 4; r++) {
        int row = m0 + wm * 32 + mf * 16 + quad * 4 + r;
        if (row < M_ROWS) {
          atomicAdd(&att[row * 2],     p[mf][r][0]);
          atomicAdd(&att[row * 2 + 1], p[mf][r][1]);
        }
      }
  }
}

// ---------------------------------------------------------------- softmax + slide_agg + local top-k
__global__ __launch_bounds__(256)
void k_soft(const float* __restrict__ att, const float* __restrict__ h,
            const int* __restrict__ slide_label, float* __restrict__ A,
            float* __restrict__ slide_agg, float* __restrict__ cand_val,
            int* __restrict__ cand_idx) {
  __shared__ float As[128][2];
  __shared__ float AIt[128];
  __shared__ float AIb[128];
  const int m0 = blockIdx.x * 128;
  const int t = threadIdx.x;
  const int sl = *slide_label;
  if (t < 128) {
    int r = m0 + t;
    float A0 = 0.f, A1 = 0.f;
    bool valid = (r < M_ROWS);
    if (valid) {
      float a0 = att[2 * r], a1 = att[2 * r + 1];
      float mx = fmaxf(a0, a1);
      float e0 = __expf(a0 - mx), e1 = __expf(a1 - mx);
      float s = e0 + e1;
      A0 = e0 / s; A1 = e1 / s;
      A[2 * r] = A0; A[2 * r + 1] = A1;
    }
    As[t][0] = A0; As[t][1] = A1;
    float ai = (sl == 0) ? A0 : A1;
    AIt[t] = valid ? ai : -3.4e38f;
    AIb[t] = valid ? ai : 3.4e38f;
  }
  __syncthreads();
  int nrows = min(128, M_ROWS - m0);
  float a00 = 0, a01 = 0, a10 = 0, a11 = 0;
  int d = t * 2;
  #pragma unroll 2
  for (int r = 0; r < nrows; r++) {
    float2 hv = *(const float2*)(h + (size_t)(m0 + r) * NCOMP + d);
    float A0 = As[r][0], A1 = As[r][1];
    a00 += A0 * hv.x; a01 += A0 * hv.y;
    a10 += A1 * hv.x; a11 += A1 * hv.y;
  }
  atomicAdd(&slide_agg[d], a00);
  atomicAdd(&slide_agg[d + 1], a01);
  atomicAdd(&slide_agg[NCOMP + d], a10);
  atomicAdd(&slide_agg[NCOMP + d + 1], a11);
  if (t < 64) {
    for (int it = 0; it < 8; it++) {
      float v0 = AIt[t], v1 = AIt[t + 64];
      float v = v0; int vi = t;
      if (v1 > v) { v = v1; vi = t + 64; }
      #pragma unroll
      for (int mask = 32; mask >= 1; mask >>= 1) {
        float ov = __shfl_xor(v, mask, 64);
        int oi = __shfl_xor(vi, mask, 64);
        if (ov > v || (ov == v && oi < vi)) { v = ov; vi = oi; }
      }
      if (t == 0) {
        cand_val[blockIdx.x * 16 + it] = v;
        cand_idx[blockIdx.x * 16 + it] = m0 + vi;
      }
      AIt[vi] = -3.4e38f;
    }
    for (int it = 0; it < 8; it++) {
      float v0 = AIb[t], v1 = AIb[t + 64];
      float v = v0; int vi = t;
      if (v1 < v) { v = v1; vi = t + 64; }
      #pragma unroll
      for (int mask = 32; mask >= 1; mask >>= 1) {
        float ov = __shfl_xor(v, mask, 64);
        int oi = __shfl_xor(vi, mask, 64);
        if (ov < v || (ov == v && oi < vi)) { v = ov; vi = oi; }
      }
      if (t == 0) {
        cand_val[blockIdx.x * 16 + 8 + it] = v;
        cand_idx[blockIdx.x * 16 + 8 + it] = m0 + vi;
      }
      AIb[vi] = 3.4e38f;
    }
  }
}

// ---------------------------------------------------------------- final: global top-k, heads
__global__ __launch_bounds__(256)
void k_final(const float* __restrict__ h, const float* __restrict__ W_ins,
             const float* __restrict__ b_ins, const float* __restrict__ W_bag,
             const float* __restrict__ b_bag, const float* __restrict__ slide_agg,
             const float* __restrict__ cand_val, const int* __restrict__ cand_idx,
             float* __restrict__ out_lab, float* __restrict__ out_insu,
             float* __restrict__ out_ins, float* __restrict__ out_slide,
             float* __restrict__ out_yprob, float* __restrict__ out_yhat) {
  __shared__ float tv[NC];
  __shared__ int   ti[NC];
  __shared__ float lv[256];
  __shared__ int   li[256];
  __shared__ int   lp[256];
  __shared__ int   ids[16];
  __shared__ float insu[16][2];
  __shared__ float ssc[2];
  const int t = threadIdx.x;

  for (int i = t; i < NC; i += 256) {
    int blk = i >> 3, j = i & 7;
    tv[i] = cand_val[blk * 16 + j];
    ti[i] = cand_idx[blk * 16 + j];
  }
  __syncthreads();
  for (int it = 0; it < 8; it++) {
    float bv = -3.4e38f; int bi = 0x7fffffff, bp = -1;
    for (int i = t; i < NC; i += 256) {
      float v = tv[i]; int idx = ti[i];
      if (v > bv || (v == bv && idx < bi)) { bv = v; bi = idx; bp = i; }
    }
    lv[t] = bv; li[t] = bi; lp[t] = bp;
    __syncthreads();
    for (int s = 128; s >= 1; s >>= 1) {
      if (t < s) {
        float ov = lv[t + s]; int oi = li[t + s];
        if (ov > lv[t] || (ov == lv[t] && oi < li[t])) { lv[t] = ov; li[t] = oi; lp[t] = lp[t + s]; }
      }
      __syncthreads();
    }
    if (t == 0) { ids[it] = li[0]; tv[lp[0]] = -3.4e38f; }
    __syncthreads();
  }
  for (int i = t; i < NC; i += 256) {
    int blk = i >> 3, j = i & 7;
    tv[i] = cand_val[blk * 16 + 8 + j];
    ti[i] = cand_idx[blk * 16 + 8 + j];
  }
  __syncthreads();
  for (int it = 0; it < 8; it++) {
    float bv = 3.4e38f; int bi = 0x7fffffff, bp = -1;
    for (int i = t; i < NC; i += 256) {
      float v = tv[i]; int idx = ti[i];
      if (v < bv || (v == bv && idx < bi)) { bv = v; bi = idx; bp = i; }
    }
    lv[t] = bv; li[t] = bi; lp[t] = bp;
    __syncthreads();
    for (int s = 128; s >= 1; s >>= 1) {
      if (t < s) {
        float ov = lv[t + s]; int oi = li[t + s];
        if (ov < lv[t] || (ov == lv[t] && oi < li[t])) { lv[t] = ov; li[t] = oi; lp[t] = lp[t + s]; }
      }
      __syncthreads();
    }
    if (t == 0) { ids[8 + it] = li[0]; tv[lp[0]] = 3.4e38f; }
    __syncthreads();
  }
  {
    int g = t >> 3, j = t & 7;
    int row = g >> 1, cls = g & 1;
    int id = ids[row];
    float dot = 0.f;
    for (int dd = j; dd < NCOMP; dd += 8)
      dot += h[(size_t)id * NCOMP + dd] * W_ins[dd * 2 + cls];
    #pragma unroll
    for (int mask = 1; mask < 8; mask <<= 1)
      dot += __shfl_xor(dot, mask, 64);
    if (j == 0) insu[row][cls] = dot + b_ins[cls];
  }
  __syncthreads();
  if (t < 16) {
    float u0 = insu[t][0], u1 = insu[t][1];
    out_insu[t * 2] = u0; out_insu[t * 2 + 1] = u1;
    float mx = fmaxf(u0, u1);
    float e0 = __expf(u0 - mx), e1 = __expf(u1 - mx);
    float s = e0 + e1;
    out_ins[t * 2] = e0 / s; out_ins[t * 2 + 1] = e1 / s;
    out_lab[t] = (t < 8) ? 1.0f : 0.0f;
  }
  if (t < 64) {
    int c = t >> 5, j = t & 31;
    float dot = 0.f;
    for (int dd = j; dd < NCOMP; dd += 32)
      dot += slide_agg[c * NCOMP + dd] * W_bag[dd];
    #pragma unroll
    for (int mask = 1; mask < 32; mask <<= 1)
      dot += __shfl_xor(dot, mask, 64);
    if (j == 0) ssc[c] = dot + b_bag[0];
  }
  __syncthreads();
  if (t == 0) {
    float s0 = ssc[0], s1 = ssc[1];
    out_slide[0] = s0; out_slide[1] = s1;
    float mx = fmaxf(s0, s1);
    float e0 = __expf(s0 - mx), e1 = __expf(s1 - mx);
    float s = e0 + e1;
    out_yprob[0] = e0 / s; out_yprob[1] = e1 / s;
    out_yhat[0] = (s1 > s0) ? 1.0f : 0.0f;
  }
}

// ---------------------------------------------------------------- launch
extern "C" void kernel_launch(void* const* d_in, const int* in_sizes, int n_in,
                              void* d_out, int out_size, void* d_ws, size_t ws_size,
                              hipStream_t stream) {
  const float* x     = (const float*)d_in[0];
  const int*   slide = (const int*)d_in[1];
  const float* Wc    = (const float*)d_in[2];
  const float* bc    = (const float*)d_in[3];
  const float* W1    = (const float*)d_in[4];
  const float* b1    = (const float*)d_in[5];
  const float* W2    = (const float*)d_in[6];
  const float* b2    = (const float*)d_in[7];
  const float* W3    = (const float*)d_in[8];
  const float* b3    = (const float*)d_in[9];
  const float* W_ins = (const float*)d_in[10];
  const float* b_ins = (const float*)d_in[11];
  const float* W_bag = (const float*)d_in[12];
  const float* b_bag = (const float*)d_in[13];

  float* out = (float*)d_out;
  float* att     = out;
  float* A       = out + 200000;
  float* h       = out + 400000;
  float* o_lab   = out + 51600000;
  float* o_insu  = out + 51600016;
  float* o_ins   = out + 51600048;
  float* o_slide = out + 51600080;
  float* o_yprob = out + 51600082;
  float* o_yhat  = out + 51600084;

  char* ws = (char*)d_ws;
  unsigned short* WcT = (unsigned short*)(ws + WS_WCT);
  unsigned short* W1T = (unsigned short*)(ws + WS_W1T);
  unsigned short* W2T = (unsigned short*)(ws + WS_W2T);
  float* slide_agg = (float*)(ws + WS_SAGG);
  float* cand_val  = (float*)(ws + WS_CVAL);
  int*   cand_idx  = (int*)(ws + WS_CIDX);
  unsigned short* xbf = (unsigned short*)(ws + WS_XBF);
  unsigned short* hbf = (unsigned short*)(ws + WS_HBF);

  if (ws_size >= WS_REQ) {
    k_prep2<<<2048, 256, 0, stream>>>(x, Wc, W1, W2, b3, xbf, WcT, W1T, W2T, slide_agg, att);
    k_gemm1n<<<3136, 256, 0, stream>>>(xbf, WcT, bc, h, hbf);
    k_gemm2n<<<1568, 512, 0, stream>>>(hbf, W1T, W2T, b1, b2, W3, att);
  } else {
    k_prep<<<512, 256, 0, stream>>>(Wc, W1, W2, b3, WcT, W1T, W2T, slide_agg, att);
    k_gemm1<<<3136, 256, 0, stream>>>(x, WcT, bc, h);
    k_gemm2<<<1568, 512, 0, stream>>>(h, W1T, W2T, b1, b2, W3, att);
  }
  k_soft<<<NB, 256, 0, stream>>>(att, h, slide, A, slide_agg, cand_val, cand_idx);
  k_final<<<1, 256, 0, stream>>>(h, W_ins, b_ins, W_bag, b_bag, slide_agg,
                                 cand_val, cand_idx, o_lab, o_insu, o_ins,
                                 o_slide, o_yprob, o_yhat);
}

// Round 2
// 1068.389 us; speedup vs baseline: 1.2166x; 1.0400x over previous
//
#include <hip/hip_runtime.h>
#include <hip/hip_bf16.h>

#define M_ROWS 100000
#define NFEAT 1024
#define NCOMP 512
#define NHID 256
#define NB 782            // ceil(100000/128)
#define NC (NB * 8)

// workspace layout (bytes)
#define WS_WCT   0
#define WS_W1T   1048576
#define WS_W2T   1310720
#define WS_SAGG  1572864
#define WS_CVAL  1576960
#define WS_CIDX  1627008
#define WS_HBF   1677312ULL                      // h in bf16: 100000*512*2 = 102.4 MB
#define WS_REQ   (WS_HBF + 102400000ULL + 262144ULL)

using bf16x8 = __attribute__((ext_vector_type(8))) __bf16;
using f32x4  = __attribute__((ext_vector_type(4))) float;

__device__ inline unsigned short f2bf(float f) {
  return __builtin_bit_cast(unsigned short, (__bf16)f);
}

// global -> LDS direct copy, 16 B per lane. LDS dest is wave-uniform base + lane*16;
// global source address is per-lane.
__device__ __forceinline__ void g2l16(const void* g, void* l) {
  __builtin_amdgcn_global_load_lds(
      (const __attribute__((address_space(1))) unsigned int*)(unsigned long long)g,
      (__attribute__((address_space(3))) unsigned int*)(unsigned int)(unsigned long long)l,
      16, 0, 0);
}

// ---------------------------------------------------------------- prep: weights only
__global__ void k_prep(const float* __restrict__ Wc, const float* __restrict__ W1,
                       const float* __restrict__ W2, const float* __restrict__ b3,
                       unsigned short* __restrict__ WcT, unsigned short* __restrict__ W1T,
                       unsigned short* __restrict__ W2T, float* __restrict__ slide_agg,
                       float* __restrict__ att) {
  int tid = blockIdx.x * blockDim.x + threadIdx.x;
  int stride = gridDim.x * blockDim.x;
  for (int i = tid; i < NCOMP * NFEAT; i += stride) {   // WcT[n][k] = Wc[k][n]
    int n = i >> 10, k = i & (NFEAT - 1);
    WcT[i] = f2bf(Wc[k * NCOMP + n]);
  }
  for (int i = tid; i < NHID * NCOMP; i += stride) {    // W1T/W2T [n][k]
    int n = i >> 9, k = i & (NCOMP - 1);
    W1T[i] = f2bf(W1[k * NHID + n]);
    W2T[i] = f2bf(W2[k * NHID + n]);
  }
  for (int i = tid; i < 2 * NCOMP; i += stride) slide_agg[i] = 0.f;
  float b30 = b3[0], b31 = b3[1];
  for (int i = tid; i < M_ROWS; i += stride) {
    *(float2*)(att + 2 * i) = make_float2(b30, b31);
  }
}

// ---------------------------------------------------------------- GEMM1 (m97 structure):
// h = relu(x@Wc+bc). A staged as f32 via global_load_lds, converted to bf16 at
// fragment load (v_cvt_pk_bf16_f32); B staged as bf16. Linear LDS, 2 barriers/K-step.
__global__ __launch_bounds__(256, 2)
void k_gemm1n(const float* __restrict__ x, const unsigned short* __restrict__ WcT,
              const float* __restrict__ bc, float* __restrict__ h,
              unsigned short* __restrict__ hbf) {
  __shared__ float Af[128 * 64];            // 32 KB
  __shared__ unsigned short Bl[128 * 64];   // 16 KB
  const int xcd = blockIdx.x & 7;
  const int local = blockIdx.x >> 3;
  const int nt = local & 3;
  const int mt = (local >> 2) * 8 + xcd;
  if (mt >= NB) return;
  const int m0 = mt * 128, n0 = nt * 128;
  const int t = threadIdx.x;
  const int wave = t >> 6, lane = t & 63;
  const int wm = wave & 1, wn = wave >> 1;
  const int lo = lane & 15, quad = lane >> 4;

  // A staging: 32 chunks of 4 rows x 64 f32 (1 KB each); wave w stages chunks 8w..8w+7
  const int ar = lane >> 4;              // row within 4-row chunk
  const int ac = (lane & 15) * 4;        // float offset within row
  // B staging: 16 chunks of 8 rows x 64 bf16 (1 KB each); wave w stages chunks 4w..4w+3
  const int br = lane >> 3;
  const int bch = (lane & 7) * 8;
  const unsigned short* Bg = WcT + (size_t)(n0 + wave * 32 + br) * NFEAT + bch;
  float* Afw = &Af[wave * 8 * 256];
  unsigned short* Blw = &Bl[wave * 4 * 512];

  f32x4 acc[4][4] = {};

  for (int kk = 0; kk < NFEAT; kk += 64) {
    #pragma unroll
    for (int i = 0; i < 8; i++) {
      int grow = m0 + wave * 32 + i * 4 + ar;
      if (grow > M_ROWS - 1) grow = M_ROWS - 1;   // clamp: stay in-bounds, rows masked at C-write
      g2l16(x + (size_t)grow * NFEAT + kk + ac, Afw + i * 256);
    }
    #pragma unroll
    for (int i = 0; i < 4; i++)
      g2l16(Bg + (size_t)(i * 8) * NFEAT + kk, Blw + i * 512);
    asm volatile("s_waitcnt vmcnt(0)" ::: "memory");
    __syncthreads();

    #pragma unroll
    for (int ks = 0; ks < 2; ks++) {
      bf16x8 af[4], bfr[4];
      #pragma unroll
      for (int mf = 0; mf < 4; mf++) {
        const float* ap = &Af[(wm * 64 + mf * 16 + lo) * 64 + ks * 32 + quad * 8];
        f32x4 a0 = *(const f32x4*)ap;
        f32x4 a1 = *(const f32x4*)(ap + 4);
        bf16x8 v;
        #pragma unroll
        for (int j = 0; j < 4; j++) { v[j] = (__bf16)a0[j]; v[j + 4] = (__bf16)a1[j]; }
        af[mf] = v;
      }
      #pragma unroll
      for (int nf = 0; nf < 4; nf++)
        bfr[nf] = *(const bf16x8*)(&Bl[(wn * 64 + nf * 16 + lo) * 64 + ks * 32 + quad * 8]);
      #pragma unroll
      for (int mf = 0; mf < 4; mf++)
        #pragma unroll
        for (int nf = 0; nf < 4; nf++)
          acc[mf][nf] = __builtin_amdgcn_mfma_f32_16x16x32_bf16(af[mf], bfr[nf], acc[mf][nf], 0, 0, 0);
    }
    __syncthreads();
  }
  #pragma unroll
  for (int nf = 0; nf < 4; nf++) {
    int col = n0 + wn * 64 + nf * 16 + lo;
    float bias = bc[col];
    #pragma unroll
    for (int mf = 0; mf < 4; mf++) {
      int rb = m0 + wm * 64 + mf * 16 + quad * 4;
      #pragma unroll
      for (int r = 0; r < 4; r++) {
        int row = rb + r;
        if (row < M_ROWS) {
          float v = fmaxf(acc[mf][nf][r] + bias, 0.f);
          h[(size_t)row * NCOMP + col] = v;
          hbf[(size_t)row * NCOMP + col] = f2bf(v);
        }
      }
    }
  }
}

// ---------------------------------------------------------------- GEMM2 (m97 structure):
// gated attention partials; A = h_bf16, B1/B2 = W1T/W2T, all via global_load_lds.
__global__ __launch_bounds__(512, 2)
void k_gemm2n(const unsigned short* __restrict__ hbf, const unsigned short* __restrict__ W1T,
              const unsigned short* __restrict__ W2T, const float* __restrict__ b1,
              const float* __restrict__ b2, const float* __restrict__ W3,
              float* __restrict__ att) {
  __shared__ unsigned short Al[128 * 64];
  __shared__ unsigned short B1l[128 * 64];
  __shared__ unsigned short B2l[128 * 64];
  const int xcd = blockIdx.x & 7;
  const int local = blockIdx.x >> 3;
  const int nt = local & 1;
  const int mt = (local >> 1) * 8 + xcd;
  if (mt >= NB) return;
  const int m0 = mt * 128, n0 = nt * 128;
  const int t = threadIdx.x;
  const int wave = t >> 6, lane = t & 63;
  const int wm = wave & 3, wn = wave >> 2;   // 4 m-waves x 2 n-waves, 32x64 per wave
  const int lo = lane & 15, quad = lane >> 4;

  const int srow = lane >> 3;
  const int scol = (lane & 7) * 8;
  const unsigned short* Ag  = hbf + (size_t)(m0 + wave * 16 + srow) * NCOMP + scol;
  const unsigned short* B1g = W1T + (size_t)(n0 + wave * 16 + srow) * NCOMP + scol;
  const unsigned short* B2g = W2T + (size_t)(n0 + wave * 16 + srow) * NCOMP + scol;
  unsigned short* Alw = &Al[wave * 1024];
  unsigned short* B1w = &B1l[wave * 1024];
  unsigned short* B2w = &B2l[wave * 1024];

  f32x4 acc1[2][4] = {};
  f32x4 acc2[2][4] = {};

  for (int kk = 0; kk < NCOMP; kk += 64) {
    #pragma unroll
    for (int i = 0; i < 2; i++) {
      g2l16(Ag  + (size_t)(i * 8) * NCOMP + kk, Alw + i * 512);
      g2l16(B1g + (size_t)(i * 8) * NCOMP + kk, B1w + i * 512);
      g2l16(B2g + (size_t)(i * 8) * NCOMP + kk, B2w + i * 512);
    }
    asm volatile("s_waitcnt vmcnt(0)" ::: "memory");
    __syncthreads();
    #pragma unroll
    for (int ks = 0; ks < 2; ks++) {
      bf16x8 af[2];
      #pragma unroll
      for (int mf = 0; mf < 2; mf++)
        af[mf] = *(const bf16x8*)(&Al[(wm * 32 + mf * 16 + lo) * 64 + ks * 32 + quad * 8]);
      #pragma unroll
      for (int nf = 0; nf < 4; nf++) {
        bf16x8 b1f = *(const bf16x8*)(&B1l[(wn * 64 + nf * 16 + lo) * 64 + ks * 32 + quad * 8]);
        acc1[0][nf] = __builtin_amdgcn_mfma_f32_16x16x32_bf16(af[0], b1f, acc1[0][nf], 0, 0, 0);
        acc1[1][nf] = __builtin_amdgcn_mfma_f32_16x16x32_bf16(af[1], b1f, acc1[1][nf], 0, 0, 0);
        bf16x8 b2f = *(const bf16x8*)(&B2l[(wn * 64 + nf * 16 + lo) * 64 + ks * 32 + quad * 8]);
        acc2[0][nf] = __builtin_amdgcn_mfma_f32_16x16x32_bf16(af[0], b2f, acc2[0][nf], 0, 0, 0);
        acc2[1][nf] = __builtin_amdgcn_mfma_f32_16x16x32_bf16(af[1], b2f, acc2[1][nf], 0, 0, 0);
      }
    }
    __syncthreads();
  }
  // a = tanh(G1+b1)*sigmoid(G2+b2); partial att = a @ W3 (reduce over this block's 128 cols)
  float p[2][4][2] = {};
  #pragma unroll
  for (int nf = 0; nf < 4; nf++) {
    int col = n0 + wn * 64 + nf * 16 + lo;
    float bb1 = b1[col], bb2 = b2[col];
    float w30 = W3[col * 2], w31 = W3[col * 2 + 1];
    #pragma unroll
    for (int mf = 0; mf < 2; mf++)
      #pragma unroll
      for (int r = 0; r < 4; r++) {
        float g1 = acc1[mf][nf][r] + bb1;
        float g2 = acc2[mf][nf][r] + bb2;
        float e = __expf(-2.f * g1);
        float th = (1.f - e) / (1.f + e);
        float sg = 1.f / (1.f + __expf(-g2));
        float a = th * sg;
        p[mf][r][0] += a * w30;
        p[mf][r][1] += a * w31;
      }
  }
  #pragma unroll
  for (int mask = 1; mask < 16; mask <<= 1)
    #pragma unroll
    for (int mf = 0; mf < 2; mf++)
      #pragma unroll
      for (int r = 0; r < 4; r++) {
        p[mf][r][0] += __shfl_xor(p[mf][r][0], mask, 64);
        p[mf][r][1] += __shfl_xor(p[mf][r][1], mask, 64);
      }
  if (lo == 0) {
    #pragma unroll
    for (int mf = 0; mf < 2; mf++)
      #pragma unroll
      for (int r = 0; r < 4; r++) {
        int row = m0 + wm * 32 + mf * 16 + quad * 4 + r;
        if (row < M_ROWS) {
          atomicAdd(&att[row * 2],     p[mf][r][0]);
          atomicAdd(&att[row * 2 + 1], p[mf][r][1]);
        }
      }
  }
}

// ---------------------------------------------------------------- softmax + slide_agg + local top-k
__global__ __launch_bounds__(256)
void k_soft(const float* __restrict__ att, const unsigned short* __restrict__ hbf,
            const int* __restrict__ slide_label, float* __restrict__ A,
            float* __restrict__ slide_agg, float* __restrict__ cand_val,
            int* __restrict__ cand_idx) {
  __shared__ float As[128][2];
  __shared__ float AIt[128];
  __shared__ float AIb[128];
  const int m0 = blockIdx.x * 128;
  const int t = threadIdx.x;
  const int sl = *slide_label;
  if (t < 128) {
    int r = m0 + t;
    float A0 = 0.f, A1 = 0.f;
    bool valid = (r < M_ROWS);
    if (valid) {
      float a0 = att[2 * r], a1 = att[2 * r + 1];
      float mx = fmaxf(a0, a1);
      float e0 = __expf(a0 - mx), e1 = __expf(a1 - mx);
      float s = e0 + e1;
      A0 = e0 / s; A1 = e1 / s;
      A[2 * r] = A0; A[2 * r + 1] = A1;
    }
    As[t][0] = A0; As[t][1] = A1;
    float ai = (sl == 0) ? A0 : A1;
    AIt[t] = valid ? ai : -3.4e38f;
    AIb[t] = valid ? ai : 3.4e38f;
  }
  __syncthreads();
  // partial slide_agg[c][d] += A[r][c]*h[r][d]  (h read as bf16, exact upconvert)
  int nrows = min(128, M_ROWS - m0);
  float a00 = 0, a01 = 0, a10 = 0, a11 = 0;
  int d = t * 2;
  #pragma unroll 2
  for (int r = 0; r < nrows; r++) {
    unsigned int u = *(const unsigned int*)(hbf + (size_t)(m0 + r) * NCOMP + d);
    float hx = __uint_as_float((u & 0xffffu) << 16);
    float hy = __uint_as_float(u & 0xffff0000u);
    float A0 = As[r][0], A1 = As[r][1];
    a00 += A0 * hx; a01 += A0 * hy;
    a10 += A1 * hx; a11 += A1 * hy;
  }
  atomicAdd(&slide_agg[d], a00);
  atomicAdd(&slide_agg[d + 1], a01);
  atomicAdd(&slide_agg[NCOMP + d], a10);
  atomicAdd(&slide_agg[NCOMP + d + 1], a11);
  // local top-8 / bottom-8 (wave 0, butterfly argmax, ties -> lower index)
  if (t < 64) {
    for (int it = 0; it < 8; it++) {
      float v0 = AIt[t], v1 = AIt[t + 64];
      float v = v0; int vi = t;
      if (v1 > v) { v = v1; vi = t + 64; }
      #pragma unroll
      for (int mask = 32; mask >= 1; mask >>= 1) {
        float ov = __shfl_xor(v, mask, 64);
        int oi = __shfl_xor(vi, mask, 64);
        if (ov > v || (ov == v && oi < vi)) { v = ov; vi = oi; }
      }
      if (t == 0) {
        cand_val[blockIdx.x * 16 + it] = v;
        cand_idx[blockIdx.x * 16 + it] = m0 + vi;
      }
      AIt[vi] = -3.4e38f;
    }
    for (int it = 0; it < 8; it++) {
      float v0 = AIb[t], v1 = AIb[t + 64];
      float v = v0; int vi = t;
      if (v1 < v) { v = v1; vi = t + 64; }
      #pragma unroll
      for (int mask = 32; mask >= 1; mask >>= 1) {
        float ov = __shfl_xor(v, mask, 64);
        int oi = __shfl_xor(vi, mask, 64);
        if (ov < v || (ov == v && oi < vi)) { v = ov; vi = oi; }
      }
      if (t == 0) {
        cand_val[blockIdx.x * 16 + 8 + it] = v;
        cand_idx[blockIdx.x * 16 + 8 + it] = m0 + vi;
      }
      AIb[vi] = 3.4e38f;
    }
  }
}

// ---------------------------------------------------------------- final: global top-k, heads
__global__ __launch_bounds__(256)
void k_final(const float* __restrict__ h, const float* __restrict__ W_ins,
             const float* __restrict__ b_ins, const float* __restrict__ W_bag,
             const float* __restrict__ b_bag, const float* __restrict__ slide_agg,
             const float* __restrict__ cand_val, const int* __restrict__ cand_idx,
             float* __restrict__ out_lab, float* __restrict__ out_insu,
             float* __restrict__ out_ins, float* __restrict__ out_slide,
             float* __restrict__ out_yprob, float* __restrict__ out_yhat) {
  __shared__ float tv[NC];
  __shared__ int   ti[NC];
  __shared__ float lv[256];
  __shared__ int   li[256];
  __shared__ int   lp[256];
  __shared__ int   ids[16];
  __shared__ float insu[16][2];
  __shared__ float ssc[2];
  const int t = threadIdx.x;

  for (int i = t; i < NC; i += 256) {
    int blk = i >> 3, j = i & 7;
    tv[i] = cand_val[blk * 16 + j];
    ti[i] = cand_idx[blk * 16 + j];
  }
  __syncthreads();
  for (int it = 0; it < 8; it++) {
    float bv = -3.4e38f; int bi = 0x7fffffff, bp = -1;
    for (int i = t; i < NC; i += 256) {
      float v = tv[i]; int idx = ti[i];
      if (v > bv || (v == bv && idx < bi)) { bv = v; bi = idx; bp = i; }
    }
    lv[t] = bv; li[t] = bi; lp[t] = bp;
    __syncthreads();
    for (int s = 128; s >= 1; s >>= 1) {
      if (t < s) {
        float ov = lv[t + s]; int oi = li[t + s];
        if (ov > lv[t] || (ov == lv[t] && oi < li[t])) { lv[t] = ov; li[t] = oi; lp[t] = lp[t + s]; }
      }
      __syncthreads();
    }
    if (t == 0) { ids[it] = li[0]; tv[lp[0]] = -3.4e38f; }
    __syncthreads();
  }
  for (int i = t; i < NC; i += 256) {
    int blk = i >> 3, j = i & 7;
    tv[i] = cand_val[blk * 16 + 8 + j];
    ti[i] = cand_idx[blk * 16 + 8 + j];
  }
  __syncthreads();
  for (int it = 0; it < 8; it++) {
    float bv = 3.4e38f; int bi = 0x7fffffff, bp = -1;
    for (int i = t; i < NC; i += 256) {
      float v = tv[i]; int idx = ti[i];
      if (v < bv || (v == bv && idx < bi)) { bv = v; bi = idx; bp = i; }
    }
    lv[t] = bv; li[t] = bi; lp[t] = bp;
    __syncthreads();
    for (int s = 128; s >= 1; s >>= 1) {
      if (t < s) {
        float ov = lv[t + s]; int oi = li[t + s];
        if (ov < lv[t] || (ov == lv[t] && oi < li[t])) { lv[t] = ov; li[t] = oi; lp[t] = lp[t + s]; }
      }
      __syncthreads();
    }
    if (t == 0) { ids[8 + it] = li[0]; tv[lp[0]] = 3.4e38f; }
    __syncthreads();
  }
  {
    int g = t >> 3, j = t & 7;
    int row = g >> 1, cls = g & 1;
    int id = ids[row];
    float dot = 0.f;
    for (int dd = j; dd < NCOMP; dd += 8)
      dot += h[(size_t)id * NCOMP + dd] * W_ins[dd * 2 + cls];
    #pragma unroll
    for (int mask = 1; mask < 8; mask <<= 1)
      dot += __shfl_xor(dot, mask, 64);
    if (j == 0) insu[row][cls] = dot + b_ins[cls];
  }
  __syncthreads();
  if (t < 16) {
    float u0 = insu[t][0], u1 = insu[t][1];
    out_insu[t * 2] = u0; out_insu[t * 2 + 1] = u1;
    float mx = fmaxf(u0, u1);
    float e0 = __expf(u0 - mx), e1 = __expf(u1 - mx);
    float s = e0 + e1;
    out_ins[t * 2] = e0 / s; out_ins[t * 2 + 1] = e1 / s;
    out_lab[t] = (t < 8) ? 1.0f : 0.0f;
  }
  if (t < 64) {
    int c = t >> 5, j = t & 31;
    float dot = 0.f;
    for (int dd = j; dd < NCOMP; dd += 32)
      dot += slide_agg[c * NCOMP + dd] * W_bag[dd];
    #pragma unroll
    for (int mask = 1; mask < 32; mask <<= 1)
      dot += __shfl_xor(dot, mask, 64);
    if (j == 0) ssc[c] = dot + b_bag[0];
  }
  __syncthreads();
  if (t == 0) {
    float s0 = ssc[0], s1 = ssc[1];
    out_slide[0] = s0; out_slide[1] = s1;
    float mx = fmaxf(s0, s1);
    float e0 = __expf(s0 - mx), e1 = __expf(s1 - mx);
    float s = e0 + e1;
    out_yprob[0] = e0 / s; out_yprob[1] = e1 / s;
    out_yhat[0] = (s1 > s0) ? 1.0f : 0.0f;
  }
}

// ---------------------------------------------------------------- launch
extern "C" void kernel_launch(void* const* d_in, const int* in_sizes, int n_in,
                              void* d_out, int out_size, void* d_ws, size_t ws_size,
                              hipStream_t stream) {
  const float* x     = (const float*)d_in[0];
  const int*   slide = (const int*)d_in[1];
  const float* Wc    = (const float*)d_in[2];
  const float* bc    = (const float*)d_in[3];
  const float* W1    = (const float*)d_in[4];
  const float* b1    = (const float*)d_in[5];
  const float* W2    = (const float*)d_in[6];
  const float* b2    = (const float*)d_in[7];
  const float* W3    = (const float*)d_in[8];
  const float* b3    = (const float*)d_in[9];
  const float* W_ins = (const float*)d_in[10];
  const float* b_ins = (const float*)d_in[11];
  const float* W_bag = (const float*)d_in[12];
  const float* b_bag = (const float*)d_in[13];

  float* out = (float*)d_out;
  float* att     = out;                 // 200000
  float* A       = out + 200000;        // 200000
  float* h       = out + 400000;        // 51200000
  float* o_lab   = out + 51600000;
  float* o_insu  = out + 51600016;
  float* o_ins   = out + 51600048;
  float* o_slide = out + 51600080;
  float* o_yprob = out + 51600082;
  float* o_yhat  = out + 51600084;

  char* ws = (char*)d_ws;
  unsigned short* WcT = (unsigned short*)(ws + WS_WCT);
  unsigned short* W1T = (unsigned short*)(ws + WS_W1T);
  unsigned short* W2T = (unsigned short*)(ws + WS_W2T);
  float* slide_agg = (float*)(ws + WS_SAGG);
  float* cand_val  = (float*)(ws + WS_CVAL);
  int*   cand_idx  = (int*)(ws + WS_CIDX);
  unsigned short* hbf = (unsigned short*)(ws + WS_HBF);

  k_prep<<<512, 256, 0, stream>>>(Wc, W1, W2, b3, WcT, W1T, W2T, slide_agg, att);
  // gemm1 grid: 8 xcd * 4 nt * ceil(782/8)=98 -> 3136
  k_gemm1n<<<3136, 256, 0, stream>>>(x, WcT, bc, h, hbf);
  // gemm2 grid: 8 xcd * 2 nt * 98 -> 1568
  k_gemm2n<<<1568, 512, 0, stream>>>(hbf, W1T, W2T, b1, b2, W3, att);
  k_soft<<<NB, 256, 0, stream>>>(att, hbf, slide, A, slide_agg, cand_val, cand_idx);
  k_final<<<1, 256, 0, stream>>>(h, W_ins, b_ins, W_bag, b_bag, slide_agg,
                                 cand_val, cand_idx, o_lab, o_insu, o_ins,
                                 o_slide, o_yprob, o_yhat);
}